// Round 17
// baseline (138.913 us; speedup 1.0000x reference)
//
#include <hip/hip_runtime.h>
#include <math.h>

// Problem constants (from reference)
#define N_G   60000
#define N_D   40000
#define NTOT  100000          // N_G + N_D
#define DIM   64
#define E_EDGES 1600000
#define B_BATCH 4096
#define K_NEG   1
#define DECAY_F 1e-4f

#define BIN_SHIFT 10
#define BIN_SIZE (1 << BIN_SHIFT)
#define NBIN ((NTOT + BIN_SIZE - 1) >> BIN_SHIFT)   // 98 bins of 1024 rows
#define SCAT_BLOCKS 1000
#define EPB (E_EDGES / SCAT_BLOCKS)                 // 1600 edges per block
#define NBB (NBIN * SCAT_BLOCKS)                    // 98000 (block,bin) counters
#define NB2 ((NBB + 1023) / 1024)                   // 96 scan blocks
#define CONV4 (NTOT * (DIM / 4))                    // 1.6M float4 conv items
#define CPB (CONV4 / SCAT_BLOCKS)                   // 1600 conv items per block

// native 4x u32 vector for nontemporal builtins (HIP uint4 class is rejected)
typedef unsigned int u32x4 __attribute__((ext_vector_type(4)));

// bf16 helpers (storage-only; all math in fp32)
__device__ __forceinline__ float bf2f(unsigned short u) {
    return __uint_as_float(((unsigned)u) << 16);
}
__device__ __forceinline__ unsigned short f2bf(float f) {
    unsigned b = __float_as_uint(f);
    return (unsigned short)((b + 0x7FFFu + ((b >> 16) & 1u)) >> 16);
}
__device__ __forceinline__ float bflo(unsigned u) { return __uint_as_float(u << 16); }
__device__ __forceinline__ float bfhi(unsigned u) { return __uint_as_float(u & 0xFFFF0000u); }
// 4-byte edge record: (val_bf15 << 17) | col.  val >= 0 so sign bit implicit 0.
__device__ __forceinline__ float rec_val(unsigned rec) {
    return __uint_as_float((rec >> 17) << 16);
}

// ---------------------------------------------------------------------------
// k_hist1 + conv_raw fused: per-block bin histogram of its edge slice (plain
// stores to bbcnt) AND bf16-convert a slice of concat(ge,de) into rawh.
// ---------------------------------------------------------------------------
__global__ void __launch_bounds__(512) k_hist1(
        const int* __restrict__ arow, int* __restrict__ bbcnt,
        const float* __restrict__ ge, const float* __restrict__ de,
        ushort4* __restrict__ rawh) {
    __shared__ int cnt[NBIN];
    int t = threadIdx.x;
    for (int i = t; i < NBIN; i += 512) cnt[i] = 0;
    __syncthreads();
    int s = blockIdx.x * EPB, e = s + EPB;
    for (int i = s + t; i < e; i += 512)
        atomicAdd(&cnt[arow[i] >> BIN_SHIFT], 1);    // LDS atomic
    // conv slice (independent of histogram; overlaps its latency)
    int cs = blockIdx.x * CPB, ce = cs + CPB;
    for (int i = cs + t; i < ce; i += 512) {
        float4 v = (i < N_G * (DIM / 4)) ? ((const float4*)ge)[i]
                                         : ((const float4*)de)[i - N_G * (DIM / 4)];
        rawh[i] = make_ushort4(f2bf(v.x), f2bf(v.y), f2bf(v.z), f2bf(v.w));
    }
    __syncthreads();
    for (int i = t; i < NBIN; i += 512)
        bbcnt[i * SCAT_BLOCKS + blockIdx.x] = cnt[i];
}

__global__ void k_scan1g(const int* __restrict__ in, int* __restrict__ excl,
                         int* __restrict__ blocksum) {
    int gid  = blockIdx.x * 1024 + threadIdx.x;
    int lane = threadIdx.x & 63;
    int wid  = threadIdx.x >> 6;           // 16 waves
    int v = (gid < NBB) ? in[gid] : 0;
    int x = v;
    #pragma unroll
    for (int off = 1; off < 64; off <<= 1) {
        int y = __shfl_up(x, off);
        if (lane >= off) x += y;
    }
    __shared__ int wsum[16];
    if (lane == 63) wsum[wid] = x;
    __syncthreads();
    if (wid == 0) {
        int w = (lane < 16) ? wsum[lane] : 0;
        #pragma unroll
        for (int off = 1; off < 16; off <<= 1) {
            int y = __shfl_up(w, off);
            if (lane >= off) w += y;
        }
        if (lane < 16) wsum[lane] = w;
    }
    __syncthreads();
    int woff = (wid == 0) ? 0 : wsum[wid - 1];
    int incl = x + woff;
    if (gid < NBB) excl[gid] = incl - v;
    if (threadIdx.x == 1023) blocksum[blockIdx.x] = incl;
}

// scan of NB2 (=96) block sums: 128 threads = 2 waves.
__global__ void k_scan2g(const int* __restrict__ blocksum, int* __restrict__ blockoff) {
    int t = threadIdx.x;                   // 0..127
    int lane = t & 63;
    int wid  = t >> 6;
    int v = (t < NB2) ? blocksum[t] : 0;
    int x = v;
    #pragma unroll
    for (int off = 1; off < 64; off <<= 1) {
        int y = __shfl_up(x, off);
        if (lane >= off) x += y;
    }
    __shared__ int wsum[2];
    if (lane == 63) wsum[wid] = x;
    __syncthreads();
    int incl = x + ((wid == 1) ? wsum[0] : 0);
    if (t < NB2) blockoff[t] = incl - v;
}

__global__ void __launch_bounds__(512) k_binscatter(
        const int* __restrict__ arow, const int* __restrict__ acol,
        const float* __restrict__ aval, const int* __restrict__ bbbase,
        const int* __restrict__ blockoff, int2* __restrict__ tmp) {
    __shared__ int lcur[NBIN];
    int t = threadIdx.x;
    for (int i = t; i < NBIN; i += 512) {
        int idx = i * SCAT_BLOCKS + blockIdx.x;
        lcur[i] = bbbase[idx] + blockoff[idx >> 10];
    }
    __syncthreads();
    int s = blockIdx.x * EPB, e = s + EPB;
    for (int i = s + t; i < e; i += 512) {
        int r   = arow[i];
        int bin = r >> BIN_SHIFT;
        int off = atomicAdd(&lcur[bin], 1);          // LDS atomic
        int drow = r & (BIN_SIZE - 1);
        tmp[off] = make_int2((drow << 17) | acol[i], __float_as_int(aval[i]));
    }
}

// Per bin: LDS row-histogram + local scan -> row_ptr (coalesced) + final scatter
// into 4-byte compressed edge records. 1024 threads for latency hiding.
__global__ void __launch_bounds__(1024) k_binfinal(
        const int* __restrict__ bbbase, const int* __restrict__ blockoff,
        const int2* __restrict__ tmp,
        int* __restrict__ row_ptr, unsigned* __restrict__ edge_c) {
    __shared__ int hist[BIN_SIZE];                   // then reused as cursors
    __shared__ int wsum[16];
    int t = threadIdx.x;                             // 0..1023
    int bin = blockIdx.x;
    int rbase = bin << BIN_SHIFT;
    int i0 = bin * SCAT_BLOCKS;
    int binstart = bbbase[i0] + blockoff[i0 >> 10];
    int binend;
    if (bin + 1 < NBIN) {
        int i1 = (bin + 1) * SCAT_BLOCKS;
        binend = bbbase[i1] + blockoff[i1 >> 10];
    } else {
        binend = E_EDGES;
    }

    hist[t] = 0;
    __syncthreads();
    for (int i = binstart + t; i < binend; i += 1024)
        atomicAdd(&hist[((unsigned)tmp[i].x) >> 17], 1);   // LDS atomic
    __syncthreads();

    // 1024-thread exclusive scan of hist[1024]: one element per thread.
    int lane = t & 63, wid = t >> 6;
    int h = hist[t];
    int x = h;
    #pragma unroll
    for (int off = 1; off < 64; off <<= 1) {
        int y = __shfl_up(x, off);
        if (lane >= off) x += y;
    }
    if (lane == 63) wsum[wid] = x;
    __syncthreads();
    int woff = 0;
    #pragma unroll
    for (int i = 0; i < 16; ++i) if (i < wid) woff += wsum[i];
    int excl = woff + x - h;                         // exclusive prefix
    int c = binstart + excl;
    __syncthreads();                                 // done reading hist as counts
    hist[t] = c;
    if (rbase + t < NTOT) row_ptr[rbase + t] = c;
    if (bin == NBIN - 1 && t == 0) row_ptr[NTOT] = E_EDGES;
    __syncthreads();

    for (int i = binstart + t; i < binend; i += 1024) {
        int2 rec = tmp[i];
        int drow = ((unsigned)rec.x) >> 17;
        int pos  = atomicAdd(&hist[drow], 1);        // LDS atomic
        unsigned vb = (unsigned)rec.y;
        unsigned b  = (vb + 0x7FFFu + ((vb >> 16) & 1u)) >> 16;   // bf16 round
        edge_c[pos] = ((b & 0x7FFFu) << 17) | ((unsigned)rec.x & 0x1FFFFu);
    }
}

// ---------------------------------------------------------------------------
// SpMM (both hops), bf16 in/out, fp32 accumulate.
// Wave = 8 rows; group g (8 lanes) OWNS row wave*8+g; lane covers 8 dims.
// Unroll-8: 8 independent record loads + 8 gathers in flight per group.
// Nontemporal on the single-use edge stream and dst stream to keep the
// 12.8 MB gather working set resident in each XCD's 4 MB L2.
// ---------------------------------------------------------------------------
__global__ void __launch_bounds__(256) spmm_r8(
        const int* __restrict__ row_ptr, const unsigned* __restrict__ edge_c,
        const unsigned short* __restrict__ src, unsigned short* __restrict__ dst) {
    int gtid = blockIdx.x * blockDim.x + threadIdx.x;
    int wave = gtid >> 6;         // 12500 waves (100000 = 8 * 12500)
    int lane = gtid & 63;
    int g    = lane >> 3;         // which of the wave's 8 rows
    int sub  = lane & 7;          // 16B chunk of that row
    int row  = wave * 8 + g;
    int s = row_ptr[row];
    int e = row_ptr[row + 1];
    const char* srcb = (const char*)src;
    float a0 = 0.f, a1 = 0.f, a2 = 0.f, a3 = 0.f;
    float a4 = 0.f, a5 = 0.f, a6 = 0.f, a7 = 0.f;
    for (int k = s; k < e; k += 8) {
        unsigned rec[8];
        float    v[8];
        #pragma unroll
        for (int i = 0; i < 8; ++i) {
            int idx = k + i;
            int j = (idx < e) ? idx : s;             // clamp to a valid record
            rec[i] = __builtin_nontemporal_load(edge_c + j);
            v[i] = (idx < e) ? rec_val(rec[i]) : 0.0f;
        }
        uint4 d[8];
        #pragma unroll
        for (int i = 0; i < 8; ++i) {
            unsigned coff = (rec[i] & 0x1FFFFu) << 7;    // byte offset (128B row)
            d[i] = *reinterpret_cast<const uint4*>(srcb + coff + sub * 16);
        }
        #pragma unroll
        for (int i = 0; i < 8; ++i) {
            a0 = fmaf(v[i], bflo(d[i].x), a0);
            a1 = fmaf(v[i], bfhi(d[i].x), a1);
            a2 = fmaf(v[i], bflo(d[i].y), a2);
            a3 = fmaf(v[i], bfhi(d[i].y), a3);
            a4 = fmaf(v[i], bflo(d[i].z), a4);
            a5 = fmaf(v[i], bfhi(d[i].z), a5);
            a6 = fmaf(v[i], bflo(d[i].w), a6);
            a7 = fmaf(v[i], bfhi(d[i].w), a7);
        }
    }
    u32x4 o;
    o.x = (unsigned)f2bf(a0) | ((unsigned)f2bf(a1) << 16);
    o.y = (unsigned)f2bf(a2) | ((unsigned)f2bf(a3) << 16);
    o.z = (unsigned)f2bf(a4) | ((unsigned)f2bf(a5) << 16);
    o.w = (unsigned)f2bf(a6) | ((unsigned)f2bf(a7) << 16);
    __builtin_nontemporal_store(o,
        reinterpret_cast<u32x4*>(dst + (size_t)row * DIM + (size_t)sub * 8));
}

// ---------------------------------------------------------------------------
// Hop-3 pull for one row over bf16 src (lane = elem layout), 4B edge records.
// ---------------------------------------------------------------------------
__device__ __forceinline__ float pull_row_h(const int* __restrict__ row_ptr,
                                            const unsigned* __restrict__ edge_c,
                                            const unsigned short* __restrict__ src,
                                            int row, int lane) {
    int s = row_ptr[row];
    int e = row_ptr[row + 1];
    float acc0 = 0.0f, acc1 = 0.0f;
    for (int base = s; base < e; base += 8) {
        unsigned ed[8];
        #pragma unroll
        for (int i = 0; i < 8; ++i)
            ed[i] = (base + i < e) ? edge_c[base + i] : 0u;
        float a[8];
        #pragma unroll
        for (int i = 0; i < 8; ++i)
            a[i] = bf2f(src[(size_t)(ed[i] & 0x1FFFFu) * DIM + lane]);
        #pragma unroll
        for (int i = 0; i < 8; i += 2) {
            acc0 = fmaf(rec_val(ed[i]),     a[i],     acc0);
            acc1 = fmaf(rec_val(ed[i + 1]), a[i + 1], acc1);
        }
    }
    return acc0 + acc1;
}

// ---------------------------------------------------------------------------
// mean_rows: one wave per (batch, row-type). NO contended atomics.
// ---------------------------------------------------------------------------
__global__ void mean_rows(const unsigned short* __restrict__ side1h,
                          const unsigned short* __restrict__ side2h,
                          const int* __restrict__ row_ptr, const unsigned* __restrict__ edge_c,
                          const float* __restrict__ ge, const float* __restrict__ de,
                          const float* __restrict__ gt, const float* __restrict__ dt,
                          const int* __restrict__ user, const int* __restrict__ pos,
                          const int* __restrict__ neg, float* __restrict__ mrows,
                          float* __restrict__ regbuf) {
    int gtid = blockIdx.x * blockDim.x + threadIdx.x;
    int wave = gtid >> 6;                  // 0 .. 3*B-1
    int lane = gtid & 63;
    if (wave >= 3 * B_BATCH) return;
    int b = wave / 3;
    int j = wave - 3 * b;                  // 0=user, 1=pos, 2=neg

    int   row;
    float t, e0;
    if (j == 0) {
        int u = user[b];
        row = u;  t = gt[u];  e0 = ge[(size_t)u * DIM + lane];
    } else {
        int d = (j == 1) ? pos[b] : neg[b * K_NEG];
        row = N_G + d;  t = dt[d];  e0 = de[(size_t)d * DIM + lane];
    }
    float w0 = expf(-t);
    float w1 = w0 * t;
    float w2 = w1 * t * 0.5f;
    float w3 = w1 * t * t * (1.0f / 6.0f);

    float s1 = bf2f(side1h[(size_t)row * DIM + lane]);
    float s2 = bf2f(side2h[(size_t)row * DIM + lane]);
    float s3 = pull_row_h(row_ptr, edge_c, side2h, row, lane);
    float m  = 0.25f * (w0 * e0 + w1 * s1 + w2 * s2 + w3 * s3);
    mrows[(size_t)wave * DIM + lane] = m;

    float r0 = w0 * e0;
    float reg = r0 * r0;
    #pragma unroll
    for (int off = 32; off > 0; off >>= 1) reg += __shfl_down(reg, off);
    if (lane == 0) regbuf[wave] = reg;
}

// ---------------------------------------------------------------------------
// loss_dot: one wave per batch element; plain store of per-batch mf term.
// ---------------------------------------------------------------------------
__global__ void loss_dot(const float* __restrict__ mrows, float* __restrict__ mfbuf) {
    int gtid = blockIdx.x * blockDim.x + threadIdx.x;
    int b    = gtid >> 6;
    int lane = gtid & 63;
    if (b >= B_BATCH) return;
    float gm = mrows[(size_t)(3 * b + 0) * DIM + lane];
    float pm = mrows[(size_t)(3 * b + 1) * DIM + lane];
    float nm = mrows[(size_t)(3 * b + 2) * DIM + lane];
    float dotp = gm * pm;
    float dotn = gm * nm;
    #pragma unroll
    for (int off = 32; off > 0; off >>= 1) {
        dotp += __shfl_down(dotp, off);
        dotn += __shfl_down(dotn, off);
    }
    if (lane == 0) {
        float x = dotn - dotp;
        mfbuf[b] = fmaxf(x, 0.0f) + log1pf(expf(-fabsf(x)));   // log1p(exp(x))
    }
}

// ---------------------------------------------------------------------------
// final_reduce: single block sums regbuf (3B) + mfbuf (B), emits 3 outputs.
// ---------------------------------------------------------------------------
__global__ void final_reduce(const float* __restrict__ regbuf,
                             const float* __restrict__ mfbuf,
                             float* __restrict__ out) {
    int t    = threadIdx.x;                // 1024 threads = 16 waves
    int lane = t & 63;
    int wid  = t >> 6;
    float mf = 0.0f, rg = 0.0f;
    for (int i = t; i < B_BATCH; i += 1024)     mf += mfbuf[i];
    for (int i = t; i < 3 * B_BATCH; i += 1024) rg += regbuf[i];
    #pragma unroll
    for (int off = 32; off > 0; off >>= 1) {
        mf += __shfl_down(mf, off);
        rg += __shfl_down(rg, off);
    }
    __shared__ float smf[16], srg[16];
    if (lane == 0) { smf[wid] = mf; srg[wid] = rg; }
    __syncthreads();
    if (t == 0) {
        float M = 0.0f, R = 0.0f;
        #pragma unroll
        for (int i = 0; i < 16; ++i) { M += smf[i]; R += srg[i]; }
        float mfm = M / (float)B_BATCH;
        float emb = DECAY_F * (R * 0.5f) / (float)B_BATCH;
        out[0] = mfm + emb;
        out[1] = mfm;
        out[2] = emb;
    }
}

extern "C" void kernel_launch(void* const* d_in, const int* in_sizes, int n_in,
                              void* d_out, int out_size, void* d_ws, size_t ws_size,
                              hipStream_t stream) {
    const float* ge   = (const float*)d_in[0];
    const float* de   = (const float*)d_in[1];
    const float* gt   = (const float*)d_in[2];
    const float* dt   = (const float*)d_in[3];
    const float* aval = (const float*)d_in[4];
    const int*   arow = (const int*)d_in[5];
    const int*   acol = (const int*)d_in[6];
    const int*   user = (const int*)d_in[7];
    const int*   pos  = (const int*)d_in[8];
    const int*   neg  = (const int*)d_in[9];
    float* out = (float*)d_out;

    // Workspace layout (~61 MB)
    char* ws = (char*)d_ws;
    const size_t rowHBytes = (size_t)NTOT * DIM * sizeof(unsigned short);   // 12.8 MB
    unsigned short* rawh   = (unsigned short*)(ws);
    unsigned short* side1h = (unsigned short*)(ws + rowHBytes);
    unsigned short* side2h = (unsigned short*)(ws + 2 * rowHBytes);
    char* p = ws + 3 * rowHBytes;
    int2*     tmp     = (int2*)p;          p += (size_t)E_EDGES * sizeof(int2);
    unsigned* edge_c  = (unsigned*)p;      p += (size_t)E_EDGES * sizeof(unsigned);
    float*    mrows   = (float*)p;         p += (size_t)3 * B_BATCH * DIM * sizeof(float);
    int*      row_ptr = (int*)p;           p += (NTOT + 1) * sizeof(int);
    int*      bbcnt   = (int*)p;           p += (size_t)NBB * sizeof(int);
    int*      bbbase  = (int*)p;           p += (size_t)NBB * sizeof(int);
    int*      blocksum= (int*)p;           p += 128 * sizeof(int);
    int*      blockoff= (int*)p;           p += 128 * sizeof(int);
    float*    regbuf  = (float*)p;         p += (size_t)3 * B_BATCH * sizeof(float);
    float*    mfbuf   = (float*)p;

    // CSR build (conv_raw fused into hist1) — no global atomics anywhere.
    k_hist1     <<<SCAT_BLOCKS, 512, 0, stream>>>(arow, bbcnt, ge, de, (ushort4*)rawh);
    k_scan1g    <<<NB2, 1024, 0, stream>>>(bbcnt, bbbase, blocksum);
    k_scan2g    <<<1, 128, 0, stream>>>(blocksum, blockoff);
    k_binscatter<<<SCAT_BLOCKS, 512, 0, stream>>>(arow, acol, aval, bbbase, blockoff, tmp);
    k_binfinal  <<<NBIN, 1024, 0, stream>>>(bbbase, blockoff, tmp, row_ptr, edge_c);

    const int spmm_blocks = (NTOT / 8 * 64) / 256;   // 3125
    spmm_r8<<<spmm_blocks, 256, 0, stream>>>(row_ptr, edge_c, rawh,   side1h);
    spmm_r8<<<spmm_blocks, 256, 0, stream>>>(row_ptr, edge_c, side1h, side2h);

    mean_rows<<<(3 * B_BATCH * 64 + 255) / 256, 256, 0, stream>>>(
        side1h, side2h, row_ptr, edge_c, ge, de, gt, dt, user, pos, neg, mrows, regbuf);
    loss_dot<<<(B_BATCH * 64 + 255) / 256, 256, 0, stream>>>(mrows, mfbuf);
    final_reduce<<<1, 1024, 0, stream>>>(regbuf, mfbuf, out);
}

// Round 18
// 131.182 us; speedup vs baseline: 1.0589x; 1.0589x over previous
//
#include <hip/hip_runtime.h>
#include <math.h>

// Problem constants (from reference)
#define N_G   60000
#define N_D   40000
#define NTOT  100000          // N_G + N_D
#define DIM   64
#define E_EDGES 1600000
#define B_BATCH 4096
#define K_NEG   1
#define DECAY_F 1e-4f

#define BIN_SHIFT 10
#define BIN_SIZE (1 << BIN_SHIFT)
#define NBIN ((NTOT + BIN_SIZE - 1) >> BIN_SHIFT)   // 98 bins of 1024 rows
#define SCAT_BLOCKS 1000
#define EPB (E_EDGES / SCAT_BLOCKS)                 // 1600 edges per block
#define NBB (NBIN * SCAT_BLOCKS)                    // 98000 (block,bin) counters
#define NB2 ((NBB + 1023) / 1024)                   // 96 scan blocks
#define CONV4 (NTOT * (DIM / 4))                    // 1.6M float4 conv items
#define CPB (CONV4 / SCAT_BLOCKS)                   // 1600 conv items per block

// bf16 helpers (storage-only; all math in fp32)
__device__ __forceinline__ float bf2f(unsigned short u) {
    return __uint_as_float(((unsigned)u) << 16);
}
__device__ __forceinline__ unsigned short f2bf(float f) {
    unsigned b = __float_as_uint(f);
    return (unsigned short)((b + 0x7FFFu + ((b >> 16) & 1u)) >> 16);
}
__device__ __forceinline__ float bflo(unsigned u) { return __uint_as_float(u << 16); }
__device__ __forceinline__ float bfhi(unsigned u) { return __uint_as_float(u & 0xFFFF0000u); }
// 4-byte edge record: (val_bf15 << 17) | col.  val >= 0 so sign bit implicit 0.
__device__ __forceinline__ float rec_val(unsigned rec) {
    return __uint_as_float((rec >> 17) << 16);
}

// ---------------------------------------------------------------------------
// k_hist1 + conv_raw fused: per-block bin histogram of its edge slice (plain
// stores to bbcnt) AND bf16-convert a slice of concat(ge,de) into rawh.
// ---------------------------------------------------------------------------
__global__ void __launch_bounds__(512) k_hist1(
        const int* __restrict__ arow, int* __restrict__ bbcnt,
        const float* __restrict__ ge, const float* __restrict__ de,
        ushort4* __restrict__ rawh) {
    __shared__ int cnt[NBIN];
    int t = threadIdx.x;
    for (int i = t; i < NBIN; i += 512) cnt[i] = 0;
    __syncthreads();
    int s = blockIdx.x * EPB, e = s + EPB;
    for (int i = s + t; i < e; i += 512)
        atomicAdd(&cnt[arow[i] >> BIN_SHIFT], 1);    // LDS atomic
    // conv slice (independent of histogram; overlaps its latency)
    int cs = blockIdx.x * CPB, ce = cs + CPB;
    for (int i = cs + t; i < ce; i += 512) {
        float4 v = (i < N_G * (DIM / 4)) ? ((const float4*)ge)[i]
                                         : ((const float4*)de)[i - N_G * (DIM / 4)];
        rawh[i] = make_ushort4(f2bf(v.x), f2bf(v.y), f2bf(v.z), f2bf(v.w));
    }
    __syncthreads();
    for (int i = t; i < NBIN; i += 512)
        bbcnt[i * SCAT_BLOCKS + blockIdx.x] = cnt[i];
}

__global__ void k_scan1g(const int* __restrict__ in, int* __restrict__ excl,
                         int* __restrict__ blocksum) {
    int gid  = blockIdx.x * 1024 + threadIdx.x;
    int lane = threadIdx.x & 63;
    int wid  = threadIdx.x >> 6;           // 16 waves
    int v = (gid < NBB) ? in[gid] : 0;
    int x = v;
    #pragma unroll
    for (int off = 1; off < 64; off <<= 1) {
        int y = __shfl_up(x, off);
        if (lane >= off) x += y;
    }
    __shared__ int wsum[16];
    if (lane == 63) wsum[wid] = x;
    __syncthreads();
    if (wid == 0) {
        int w = (lane < 16) ? wsum[lane] : 0;
        #pragma unroll
        for (int off = 1; off < 16; off <<= 1) {
            int y = __shfl_up(w, off);
            if (lane >= off) w += y;
        }
        if (lane < 16) wsum[lane] = w;
    }
    __syncthreads();
    int woff = (wid == 0) ? 0 : wsum[wid - 1];
    int incl = x + woff;
    if (gid < NBB) excl[gid] = incl - v;
    if (threadIdx.x == 1023) blocksum[blockIdx.x] = incl;
}

// scan of NB2 (=96) block sums: 128 threads = 2 waves.
__global__ void k_scan2g(const int* __restrict__ blocksum, int* __restrict__ blockoff) {
    int t = threadIdx.x;                   // 0..127
    int lane = t & 63;
    int wid  = t >> 6;
    int v = (t < NB2) ? blocksum[t] : 0;
    int x = v;
    #pragma unroll
    for (int off = 1; off < 64; off <<= 1) {
        int y = __shfl_up(x, off);
        if (lane >= off) x += y;
    }
    __shared__ int wsum[2];
    if (lane == 63) wsum[wid] = x;
    __syncthreads();
    int incl = x + ((wid == 1) ? wsum[0] : 0);
    if (t < NB2) blockoff[t] = incl - v;
}

__global__ void __launch_bounds__(512) k_binscatter(
        const int* __restrict__ arow, const int* __restrict__ acol,
        const float* __restrict__ aval, const int* __restrict__ bbbase,
        const int* __restrict__ blockoff, int2* __restrict__ tmp) {
    __shared__ int lcur[NBIN];
    int t = threadIdx.x;
    for (int i = t; i < NBIN; i += 512) {
        int idx = i * SCAT_BLOCKS + blockIdx.x;
        lcur[i] = bbbase[idx] + blockoff[idx >> 10];
    }
    __syncthreads();
    int s = blockIdx.x * EPB, e = s + EPB;
    for (int i = s + t; i < e; i += 512) {
        int r   = arow[i];
        int bin = r >> BIN_SHIFT;
        int off = atomicAdd(&lcur[bin], 1);          // LDS atomic
        int drow = r & (BIN_SIZE - 1);
        tmp[off] = make_int2((drow << 17) | acol[i], __float_as_int(aval[i]));
    }
}

// Per bin: LDS row-histogram + local scan -> row_ptr (coalesced) + final scatter
// into 4-byte compressed edge records. 1024 threads for latency hiding.
__global__ void __launch_bounds__(1024) k_binfinal(
        const int* __restrict__ bbbase, const int* __restrict__ blockoff,
        const int2* __restrict__ tmp,
        int* __restrict__ row_ptr, unsigned* __restrict__ edge_c) {
    __shared__ int hist[BIN_SIZE];                   // then reused as cursors
    __shared__ int wsum[16];
    int t = threadIdx.x;                             // 0..1023
    int bin = blockIdx.x;
    int rbase = bin << BIN_SHIFT;
    int i0 = bin * SCAT_BLOCKS;
    int binstart = bbbase[i0] + blockoff[i0 >> 10];
    int binend;
    if (bin + 1 < NBIN) {
        int i1 = (bin + 1) * SCAT_BLOCKS;
        binend = bbbase[i1] + blockoff[i1 >> 10];
    } else {
        binend = E_EDGES;
    }

    hist[t] = 0;
    __syncthreads();
    for (int i = binstart + t; i < binend; i += 1024)
        atomicAdd(&hist[((unsigned)tmp[i].x) >> 17], 1);   // LDS atomic
    __syncthreads();

    // 1024-thread exclusive scan of hist[1024]: one element per thread.
    int lane = t & 63, wid = t >> 6;
    int h = hist[t];
    int x = h;
    #pragma unroll
    for (int off = 1; off < 64; off <<= 1) {
        int y = __shfl_up(x, off);
        if (lane >= off) x += y;
    }
    if (lane == 63) wsum[wid] = x;
    __syncthreads();
    int woff = 0;
    #pragma unroll
    for (int i = 0; i < 16; ++i) if (i < wid) woff += wsum[i];
    int excl = woff + x - h;                         // exclusive prefix
    int c = binstart + excl;
    __syncthreads();                                 // done reading hist as counts
    hist[t] = c;
    if (rbase + t < NTOT) row_ptr[rbase + t] = c;
    if (bin == NBIN - 1 && t == 0) row_ptr[NTOT] = E_EDGES;
    __syncthreads();

    for (int i = binstart + t; i < binend; i += 1024) {
        int2 rec = tmp[i];
        int drow = ((unsigned)rec.x) >> 17;
        int pos  = atomicAdd(&hist[drow], 1);        // LDS atomic
        unsigned vb = (unsigned)rec.y;
        unsigned b  = (vb + 0x7FFFu + ((vb >> 16) & 1u)) >> 16;   // bf16 round
        edge_c[pos] = ((b & 0x7FFFu) << 17) | ((unsigned)rec.x & 0x1FFFFu);
    }
}

// ---------------------------------------------------------------------------
// SpMM (both hops), bf16 in/out, fp32 accumulate.
// Wave = 8 rows; group g (8 lanes) OWNS row wave*8+g; lane covers 8 dims.
// No cross-lane reduction. Unroll-4: 4 independent record loads + gathers.
// Bound by random-line service (established R10/R11/R12/R17 nulls).
// ---------------------------------------------------------------------------
__global__ void __launch_bounds__(256) spmm_r8(
        const int* __restrict__ row_ptr, const unsigned* __restrict__ edge_c,
        const unsigned short* __restrict__ src, unsigned short* __restrict__ dst) {
    int gtid = blockIdx.x * blockDim.x + threadIdx.x;
    int wave = gtid >> 6;         // 12500 waves (100000 = 8 * 12500)
    int lane = gtid & 63;
    int g    = lane >> 3;         // which of the wave's 8 rows
    int sub  = lane & 7;          // 16B chunk of that row
    int row  = wave * 8 + g;
    int s = row_ptr[row];
    int e = row_ptr[row + 1];
    const char* srcb = (const char*)src;
    float a0 = 0.f, a1 = 0.f, a2 = 0.f, a3 = 0.f;
    float a4 = 0.f, a5 = 0.f, a6 = 0.f, a7 = 0.f;
    for (int k = s; k < e; k += 4) {
        #pragma unroll
        for (int i = 0; i < 4; ++i) {
            int idx = k + i;
            int j = (idx < e) ? idx : s;             // clamp to a valid record
            unsigned rec = edge_c[j];
            float v = (idx < e) ? rec_val(rec) : 0.0f;
            unsigned coff = (rec & 0x1FFFFu) << 7;   // byte offset of row (128B)
            uint4 d = *reinterpret_cast<const uint4*>(srcb + coff + sub * 16);
            a0 = fmaf(v, bflo(d.x), a0);
            a1 = fmaf(v, bfhi(d.x), a1);
            a2 = fmaf(v, bflo(d.y), a2);
            a3 = fmaf(v, bfhi(d.y), a3);
            a4 = fmaf(v, bflo(d.z), a4);
            a5 = fmaf(v, bfhi(d.z), a5);
            a6 = fmaf(v, bflo(d.w), a6);
            a7 = fmaf(v, bfhi(d.w), a7);
        }
    }
    uint4 o;
    o.x = (unsigned)f2bf(a0) | ((unsigned)f2bf(a1) << 16);
    o.y = (unsigned)f2bf(a2) | ((unsigned)f2bf(a3) << 16);
    o.z = (unsigned)f2bf(a4) | ((unsigned)f2bf(a5) << 16);
    o.w = (unsigned)f2bf(a6) | ((unsigned)f2bf(a7) << 16);
    *reinterpret_cast<uint4*>(dst + (size_t)row * DIM + (size_t)sub * 8) = o;
}

// ---------------------------------------------------------------------------
// Hop-3 pull for one row over bf16 src (lane = elem layout), 4B edge records.
// ---------------------------------------------------------------------------
__device__ __forceinline__ float pull_row_h(const int* __restrict__ row_ptr,
                                            const unsigned* __restrict__ edge_c,
                                            const unsigned short* __restrict__ src,
                                            int row, int lane) {
    int s = row_ptr[row];
    int e = row_ptr[row + 1];
    float acc0 = 0.0f, acc1 = 0.0f;
    for (int base = s; base < e; base += 8) {
        unsigned ed[8];
        #pragma unroll
        for (int i = 0; i < 8; ++i)
            ed[i] = (base + i < e) ? edge_c[base + i] : 0u;
        float a[8];
        #pragma unroll
        for (int i = 0; i < 8; ++i)
            a[i] = bf2f(src[(size_t)(ed[i] & 0x1FFFFu) * DIM + lane]);
        #pragma unroll
        for (int i = 0; i < 8; i += 2) {
            acc0 = fmaf(rec_val(ed[i]),     a[i],     acc0);
            acc1 = fmaf(rec_val(ed[i + 1]), a[i + 1], acc1);
        }
    }
    return acc0 + acc1;
}

// ---------------------------------------------------------------------------
// mean_rows: one wave per (batch, row-type). NO contended atomics.
// ---------------------------------------------------------------------------
__global__ void mean_rows(const unsigned short* __restrict__ side1h,
                          const unsigned short* __restrict__ side2h,
                          const int* __restrict__ row_ptr, const unsigned* __restrict__ edge_c,
                          const float* __restrict__ ge, const float* __restrict__ de,
                          const float* __restrict__ gt, const float* __restrict__ dt,
                          const int* __restrict__ user, const int* __restrict__ pos,
                          const int* __restrict__ neg, float* __restrict__ mrows,
                          float* __restrict__ regbuf) {
    int gtid = blockIdx.x * blockDim.x + threadIdx.x;
    int wave = gtid >> 6;                  // 0 .. 3*B-1
    int lane = gtid & 63;
    if (wave >= 3 * B_BATCH) return;
    int b = wave / 3;
    int j = wave - 3 * b;                  // 0=user, 1=pos, 2=neg

    int   row;
    float t, e0;
    if (j == 0) {
        int u = user[b];
        row = u;  t = gt[u];  e0 = ge[(size_t)u * DIM + lane];
    } else {
        int d = (j == 1) ? pos[b] : neg[b * K_NEG];
        row = N_G + d;  t = dt[d];  e0 = de[(size_t)d * DIM + lane];
    }
    float w0 = expf(-t);
    float w1 = w0 * t;
    float w2 = w1 * t * 0.5f;
    float w3 = w1 * t * t * (1.0f / 6.0f);

    float s1 = bf2f(side1h[(size_t)row * DIM + lane]);
    float s2 = bf2f(side2h[(size_t)row * DIM + lane]);
    float s3 = pull_row_h(row_ptr, edge_c, side2h, row, lane);
    float m  = 0.25f * (w0 * e0 + w1 * s1 + w2 * s2 + w3 * s3);
    mrows[(size_t)wave * DIM + lane] = m;

    float r0 = w0 * e0;
    float reg = r0 * r0;
    #pragma unroll
    for (int off = 32; off > 0; off >>= 1) reg += __shfl_down(reg, off);
    if (lane == 0) regbuf[wave] = reg;
}

// ---------------------------------------------------------------------------
// loss_dot: one wave per batch element; plain store of per-batch mf term.
// ---------------------------------------------------------------------------
__global__ void loss_dot(const float* __restrict__ mrows, float* __restrict__ mfbuf) {
    int gtid = blockIdx.x * blockDim.x + threadIdx.x;
    int b    = gtid >> 6;
    int lane = gtid & 63;
    if (b >= B_BATCH) return;
    float gm = mrows[(size_t)(3 * b + 0) * DIM + lane];
    float pm = mrows[(size_t)(3 * b + 1) * DIM + lane];
    float nm = mrows[(size_t)(3 * b + 2) * DIM + lane];
    float dotp = gm * pm;
    float dotn = gm * nm;
    #pragma unroll
    for (int off = 32; off > 0; off >>= 1) {
        dotp += __shfl_down(dotp, off);
        dotn += __shfl_down(dotn, off);
    }
    if (lane == 0) {
        float x = dotn - dotp;
        mfbuf[b] = fmaxf(x, 0.0f) + log1pf(expf(-fabsf(x)));   // log1p(exp(x))
    }
}

// ---------------------------------------------------------------------------
// final_reduce: single block sums regbuf (3B) + mfbuf (B), emits 3 outputs.
// ---------------------------------------------------------------------------
__global__ void final_reduce(const float* __restrict__ regbuf,
                             const float* __restrict__ mfbuf,
                             float* __restrict__ out) {
    int t    = threadIdx.x;                // 1024 threads = 16 waves
    int lane = t & 63;
    int wid  = t >> 6;
    float mf = 0.0f, rg = 0.0f;
    for (int i = t; i < B_BATCH; i += 1024)     mf += mfbuf[i];
    for (int i = t; i < 3 * B_BATCH; i += 1024) rg += regbuf[i];
    #pragma unroll
    for (int off = 32; off > 0; off >>= 1) {
        mf += __shfl_down(mf, off);
        rg += __shfl_down(rg, off);
    }
    __shared__ float smf[16], srg[16];
    if (lane == 0) { smf[wid] = mf; srg[wid] = rg; }
    __syncthreads();
    if (t == 0) {
        float M = 0.0f, R = 0.0f;
        #pragma unroll
        for (int i = 0; i < 16; ++i) { M += smf[i]; R += srg[i]; }
        float mfm = M / (float)B_BATCH;
        float emb = DECAY_F * (R * 0.5f) / (float)B_BATCH;
        out[0] = mfm + emb;
        out[1] = mfm;
        out[2] = emb;
    }
}

extern "C" void kernel_launch(void* const* d_in, const int* in_sizes, int n_in,
                              void* d_out, int out_size, void* d_ws, size_t ws_size,
                              hipStream_t stream) {
    const float* ge   = (const float*)d_in[0];
    const float* de   = (const float*)d_in[1];
    const float* gt   = (const float*)d_in[2];
    const float* dt   = (const float*)d_in[3];
    const float* aval = (const float*)d_in[4];
    const int*   arow = (const int*)d_in[5];
    const int*   acol = (const int*)d_in[6];
    const int*   user = (const int*)d_in[7];
    const int*   pos  = (const int*)d_in[8];
    const int*   neg  = (const int*)d_in[9];
    float* out = (float*)d_out;

    // Workspace layout (~61 MB)
    char* ws = (char*)d_ws;
    const size_t rowHBytes = (size_t)NTOT * DIM * sizeof(unsigned short);   // 12.8 MB
    unsigned short* rawh   = (unsigned short*)(ws);
    unsigned short* side1h = (unsigned short*)(ws + rowHBytes);
    unsigned short* side2h = (unsigned short*)(ws + 2 * rowHBytes);
    char* p = ws + 3 * rowHBytes;
    int2*     tmp     = (int2*)p;          p += (size_t)E_EDGES * sizeof(int2);
    unsigned* edge_c  = (unsigned*)p;      p += (size_t)E_EDGES * sizeof(unsigned);
    float*    mrows   = (float*)p;         p += (size_t)3 * B_BATCH * DIM * sizeof(float);
    int*      row_ptr = (int*)p;           p += (NTOT + 1) * sizeof(int);
    int*      bbcnt   = (int*)p;           p += (size_t)NBB * sizeof(int);
    int*      bbbase  = (int*)p;           p += (size_t)NBB * sizeof(int);
    int*      blocksum= (int*)p;           p += 128 * sizeof(int);
    int*      blockoff= (int*)p;           p += 128 * sizeof(int);
    float*    regbuf  = (float*)p;         p += (size_t)3 * B_BATCH * sizeof(float);
    float*    mfbuf   = (float*)p;

    // CSR build (conv_raw fused into hist1) — no global atomics anywhere.
    k_hist1     <<<SCAT_BLOCKS, 512, 0, stream>>>(arow, bbcnt, ge, de, (ushort4*)rawh);
    k_scan1g    <<<NB2, 1024, 0, stream>>>(bbcnt, bbbase, blocksum);
    k_scan2g    <<<1, 128, 0, stream>>>(blocksum, blockoff);
    k_binscatter<<<SCAT_BLOCKS, 512, 0, stream>>>(arow, acol, aval, bbbase, blockoff, tmp);
    k_binfinal  <<<NBIN, 1024, 0, stream>>>(bbbase, blockoff, tmp, row_ptr, edge_c);

    const int spmm_blocks = (NTOT / 8 * 64) / 256;   // 3125
    spmm_r8<<<spmm_blocks, 256, 0, stream>>>(row_ptr, edge_c, rawh,   side1h);
    spmm_r8<<<spmm_blocks, 256, 0, stream>>>(row_ptr, edge_c, side1h, side2h);

    mean_rows<<<(3 * B_BATCH * 64 + 255) / 256, 256, 0, stream>>>(
        side1h, side2h, row_ptr, edge_c, ge, de, gt, dt, user, pos, neg, mrows, regbuf);
    loss_dot<<<(B_BATCH * 64 + 255) / 256, 256, 0, stream>>>(mrows, mfbuf);
    final_reduce<<<1, 1024, 0, stream>>>(regbuf, mfbuf, out);
}